// Round 1
// baseline (789.642 us; speedup 1.0000x reference)
//
#include <hip/hip_runtime.h>
#include <math.h>

#define E_TOTAL 1600000
#define NN 100000
#define NG 128
#define FF 64
#define NGROUPS (E_TOTAL / 64)   // 25000 groups of 64 edges
#define GPW 7                    // groups per wave in wsum (4096 waves * 7 >= 25000)

__device__ __forceinline__ void atomicMaxFloat(float* addr, float val) {
    // valid for IEEE floats with addr initialized to -inf:
    // positives compare as signed ints; negatives compare reversed as unsigned
    if (val >= 0.0f) atomicMax((int*)addr, __float_as_int(val));
    else             atomicMin((unsigned int*)addr, (unsigned int)__float_as_int(val));
}

__global__ __launch_bounds__(256) void init_kernel(float* m, float* den, float* hg) {
    int i = blockIdx.x * blockDim.x + threadIdx.x;
    if (i < NN) { m[i] = -INFINITY; den[i] = 0.0f; }
    if (i < NG * FF) hg[i] = 0.0f;
}

// Wave processes 4 edges/iter: 16 lanes per edge, float4 loads (1KB per wave per iter).
__global__ __launch_bounds__(256) void score_kernel(
        const float4* __restrict__ feats4, const float4* __restrict__ W4,
        const float* __restrict__ b, const int* __restrict__ dst,
        float* __restrict__ s_buf, float* __restrict__ mbuf) {
    int tid  = blockIdx.x * blockDim.x + threadIdx.x;
    int lane = threadIdx.x & 63;
    int wave = tid >> 6;
    int nw   = (gridDim.x * blockDim.x) >> 6;
    int sub  = lane >> 4;      // which of the 4 edges
    int sl   = lane & 15;      // 16 lanes cover 64 floats as float4
    float4 w = W4[sl];
    float bias = b[0];
    for (int ebase = wave * 4; ebase < E_TOTAL; ebase += nw * 4) {
        int e = ebase + sub;
        float4 v = feats4[(size_t)e * 16 + sl];
        float dq = v.x * w.x + v.y * w.y + v.z * w.z + v.w * w.w;
        dq += __shfl_xor(dq, 1);
        dq += __shfl_xor(dq, 2);
        dq += __shfl_xor(dq, 4);
        dq += __shfl_xor(dq, 8);
        float sv = 0.0f; int d = -1;
        if (sl == 0) {
            sv = dq + bias;
            sv = sv > 0.0f ? sv : 0.01f * sv;   // LeakyReLU
            s_buf[e] = sv;
            d = dst[e];
        }
        // segmented max among the 4 scoring lanes (dst sorted -> equal runs contiguous)
        float sp = __shfl_up(sv, 16); int dp = __shfl_up(d, 16);
        if (sub >= 1 && dp == d) sv = fmaxf(sv, sp);
        sp = __shfl_up(sv, 32); dp = __shfl_up(d, 32);
        if (sub >= 2 && dp == d) sv = fmaxf(sv, sp);
        int dn = __shfl_down(d, 16);
        if (sl == 0 && (sub == 3 || dn != d)) atomicMaxFloat(&mbuf[d], sv);
    }
}

// ex = exp(s - m[dst]) in-place; segmented wave scan so only segment tails do atomicAdd.
__global__ __launch_bounds__(256) void expden_kernel(
        const int* __restrict__ dst, const float* __restrict__ m,
        float* __restrict__ s_buf, float* __restrict__ den) {
    int tid  = blockIdx.x * blockDim.x + threadIdx.x;
    int lane = threadIdx.x & 63;
    int stride = gridDim.x * blockDim.x;
    for (int e = tid; e < E_TOTAL; e += stride) {
        int d = dst[e];
        float ex = __expf(s_buf[e] - m[d]);
        s_buf[e] = ex;
        float acc = ex;
        #pragma unroll
        for (int off = 1; off < 64; off <<= 1) {
            float n = __shfl_up(acc, off);
            int  nd = __shfl_up(d, off);
            if (lane >= off && nd == d) acc += n;
        }
        int dnext = __shfl_down(d, 1);
        if (lane == 63 || dnext != d) atomicAdd(&den[d], acc);
    }
}

// Each wave owns GPW contiguous groups of 64 edges. lane = feature index.
__global__ __launch_bounds__(256) void wsum_kernel(
        const float* __restrict__ feats, const float* __restrict__ exbuf,
        const float* __restrict__ den, const int* __restrict__ dst,
        const int* __restrict__ gid, float* __restrict__ wout, float* __restrict__ hg) {
    int tid  = blockIdx.x * blockDim.x + threadIdx.x;
    int lane = threadIdx.x & 63;
    int wave = tid >> 6;
    int g0 = wave * GPW;
    if (g0 >= NGROUPS) return;
    int g1 = min(g0 + GPW, NGROUPS);
    float acc = 0.0f;
    int cur_g = gid[g0 * 64];
    for (int grp = g0; grp < g1; ++grp) {
        int e = grp * 64 + lane;
        float w = exbuf[e] / den[dst[e]];
        wout[e] = w;                       // coalesced weights write
        int gg = gid[e];
        const float* frow = feats + (size_t)grp * 64 * 64;
        #pragma unroll 4
        for (int j = 0; j < 64; ++j) {
            float wj = __shfl(w, j);
            int   gj = __shfl(gg, j);
            if (gj != cur_g) {             // wave-uniform branch, rare
                atomicAdd(&hg[cur_g * 64 + lane], acc);
                acc = 0.0f;
                cur_g = gj;
            }
            acc += frow[(size_t)j * 64 + lane] * wj;  // 256B coalesced per iter
        }
    }
    atomicAdd(&hg[cur_g * 64 + lane], acc);
}

extern "C" void kernel_launch(void* const* d_in, const int* in_sizes, int n_in,
                              void* d_out, int out_size, void* d_ws, size_t ws_size,
                              hipStream_t stream) {
    const float* feats = (const float*)d_in[0];
    const float* W     = (const float*)d_in[1];
    const float* b     = (const float*)d_in[2];
    const int*   dst   = (const int*)d_in[3];
    const int*   gid   = (const int*)d_in[4];

    float* out   = (float*)d_out;
    float* hg    = out;                  // [128,64]
    float* wout  = out + NG * FF;        // [E,1]

    float* s_buf = (float*)d_ws;         // E floats (s, then ex in-place)
    float* mbuf  = s_buf + E_TOTAL;      // NN floats
    float* den   = mbuf + NN;            // NN floats

    init_kernel<<<(NN + 255) / 256, 256, 0, stream>>>(mbuf, den, hg);
    score_kernel<<<1024, 256, 0, stream>>>((const float4*)feats, (const float4*)W,
                                           b, dst, s_buf, mbuf);
    expden_kernel<<<512, 256, 0, stream>>>(dst, mbuf, s_buf, den);
    wsum_kernel<<<1024, 256, 0, stream>>>(feats, s_buf, den, dst, gid, wout, hg);
}

// Round 2
// 636.292 us; speedup vs baseline: 1.2410x; 1.2410x over previous
//
#include <hip/hip_runtime.h>
#include <math.h>

#define E_TOTAL 1600000
#define NN 100000
#define NG 128
#define FF 64
#define NGROUPS (E_TOTAL / 64)   // 25000 groups of 64 edges

__global__ __launch_bounds__(256) void init_kernel(float* den, float* hg) {
    int i = blockIdx.x * blockDim.x + threadIdx.x;
    if (i < NN) den[i] = 0.0f;
    if (i < NG * FF) hg[i] = 0.0f;
}

// Fused: dot(F=64) -> LeakyReLU -> exp (no max subtraction: s bounded, fp32 safe)
// -> store ex -> segment-aggregated atomicAdd into den.
// Wave handles 4 edges/iter: 16 lanes x float4 per edge (1KB coalesced per wave-iter).
__global__ __launch_bounds__(256) void score_kernel(
        const float4* __restrict__ feats4, const float4* __restrict__ W4,
        const float* __restrict__ b, const int* __restrict__ dst,
        float* __restrict__ exbuf, float* __restrict__ den) {
    int tid  = blockIdx.x * blockDim.x + threadIdx.x;
    int lane = threadIdx.x & 63;
    int wave = tid >> 6;
    int nw   = (gridDim.x * blockDim.x) >> 6;
    int sub  = lane >> 4;      // which of the 4 edges
    int sl   = lane & 15;      // 16 lanes cover 64 floats as float4
    float4 w = W4[sl];
    float bias = b[0];
    for (int ebase = wave * 4; ebase < E_TOTAL; ebase += nw * 4) {
        int e = ebase + sub;
        float4 v = feats4[(size_t)e * 16 + sl];
        float dq = v.x * w.x + v.y * w.y + v.z * w.z + v.w * w.w;
        dq += __shfl_xor(dq, 1);
        dq += __shfl_xor(dq, 2);
        dq += __shfl_xor(dq, 4);
        dq += __shfl_xor(dq, 8);
        float ex = 0.0f; int d = -1;
        if (sl == 0) {
            float sv = dq + bias;
            sv = sv > 0.0f ? sv : 0.01f * sv;   // LeakyReLU
            ex = __expf(sv);
            exbuf[e] = ex;
            d = dst[e];
        }
        // inclusive segmented sum over scoring lanes 0,16,32,48 (dst sorted)
        float sp = __shfl_up(ex, 16); int dp = __shfl_up(d, 16);
        if (sub >= 1 && dp == d) ex += sp;
        sp = __shfl_up(ex, 32); dp = __shfl_up(d, 32);
        if (sub >= 2 && dp == d) ex += sp;
        int dn = __shfl_down(d, 16);
        if (sl == 0 && (sub == 3 || dn != d)) atomicAdd(&den[d], ex);
    }
}

// acc layout: lane l, component c <-> feature (l&15)*4+c, partial over edges
// congruent to (l>>4) mod 4. Flushed cross-lane-group at graph boundaries only.
__device__ __forceinline__ void flush_acc(float4& acc, int cur_g, int lane,
                                          float* __restrict__ hg) {
    acc.x += __shfl_xor(acc.x, 16); acc.y += __shfl_xor(acc.y, 16);
    acc.z += __shfl_xor(acc.z, 16); acc.w += __shfl_xor(acc.w, 16);
    acc.x += __shfl_xor(acc.x, 32); acc.y += __shfl_xor(acc.y, 32);
    acc.z += __shfl_xor(acc.z, 32); acc.w += __shfl_xor(acc.w, 32);
    if (lane < 16) {
        float* p = hg + cur_g * 64 + lane * 4;
        atomicAdd(p + 0, acc.x); atomicAdd(p + 1, acc.y);
        atomicAdd(p + 2, acc.z); atomicAdd(p + 3, acc.w);
    }
    acc.x = acc.y = acc.z = acc.w = 0.0f;
}

__global__ __launch_bounds__(256) void wsum_kernel(
        const float4* __restrict__ feats4, const float* __restrict__ exbuf,
        const float* __restrict__ den, const int* __restrict__ dst,
        const int* __restrict__ gid, float* __restrict__ wout,
        float* __restrict__ hg) {
    int tid  = blockIdx.x * blockDim.x + threadIdx.x;
    int lane = threadIdx.x & 63;
    int wave = tid >> 6;
    int nwaves = (gridDim.x * blockDim.x) >> 6;
    int gpw = (NGROUPS + nwaves - 1) / nwaves;
    int g0 = wave * gpw;
    if (g0 >= NGROUPS) return;
    int g1 = min(g0 + gpw, NGROUPS);
    int q = lane >> 4;
    float4 acc = {0.f, 0.f, 0.f, 0.f};
    int cur_g = -1;
    for (int grp = g0; grp < g1; ++grp) {
        int e = grp * 64 + lane;
        float w = exbuf[e] / den[dst[e]];
        wout[e] = w;                         // coalesced weights write
        int gg = gid[e];
        int gfirst = __builtin_amdgcn_readfirstlane(gg);
        bool uni = (__ballot(gg != gfirst) == 0ULL);
        const float4* frow = feats4 + (size_t)grp * 64 * 16;
        if (uni) {                            // 99.5% of groups
            if (gfirst != cur_g) {
                if (cur_g >= 0) flush_acc(acc, cur_g, lane, hg);
                cur_g = gfirst;
            }
            #pragma unroll 4
            for (int it = 0; it < 16; ++it) {
                float we = __shfl(w, it * 4 + q);       // edge it*4+q's weight
                float4 v = frow[it * 64 + lane];        // 1KB coalesced
                acc.x += v.x * we; acc.y += v.y * we;
                acc.z += v.z * we; acc.w += v.w * we;
            }
        } else {                              // boundary group, rare
            int sl = lane & 15;
            for (int j = 0; j < 64; ++j) {
                int gj = __shfl(gg, j);
                if (gj != cur_g) {
                    if (cur_g >= 0) flush_acc(acc, cur_g, lane, hg);
                    cur_g = gj;
                }
                if (q == (j & 3)) {
                    float we = __shfl(w, j);
                    float4 v = frow[j * 16 + sl];
                    acc.x += v.x * we; acc.y += v.y * we;
                    acc.z += v.z * we; acc.w += v.w * we;
                }
            }
        }
    }
    if (cur_g >= 0) flush_acc(acc, cur_g, lane, hg);
}

extern "C" void kernel_launch(void* const* d_in, const int* in_sizes, int n_in,
                              void* d_out, int out_size, void* d_ws, size_t ws_size,
                              hipStream_t stream) {
    const float* feats = (const float*)d_in[0];
    const float* W     = (const float*)d_in[1];
    const float* b     = (const float*)d_in[2];
    const int*   dst   = (const int*)d_in[3];
    const int*   gid   = (const int*)d_in[4];

    float* out   = (float*)d_out;
    float* hg    = out;                  // [128,64]
    float* wout  = out + NG * FF;        // [E,1]

    float* exbuf = (float*)d_ws;         // E floats
    float* den   = exbuf + E_TOTAL;      // NN floats

    init_kernel<<<(NN + 255) / 256, 256, 0, stream>>>(den, hg);
    score_kernel<<<2048, 256, 0, stream>>>((const float4*)feats, (const float4*)W,
                                           b, dst, exbuf, den);
    wsum_kernel<<<1024, 256, 0, stream>>>((const float4*)feats, exbuf, den,
                                          dst, gid, wout, hg);
}